// Round 1
// baseline (154837.646 us; speedup 1.0000x reference)
//
#include <hip/hip_runtime.h>
#include <math.h>

#define TT 2048
#define BB 32
#define HH 512

// ---------------- input-projection GEMM: OUT[r,:] = X[r,:]@W + bias ----------------
// 32 rows per WG staged in LDS; safe for in-place X==OUT (each WG reads only its own
// rows, fully staged before any write).
template<int K>
__global__ void __launch_bounds__(256)
ih_gemm(const float* X, const float* __restrict__ W,
        const float* __restrict__ bias, float* OUT)
{
    __shared__ float xt[32][K];
    const int wg  = (int)blockIdx.x;
    const int tid = (int)threadIdx.x;
    const long row0 = (long)wg * 32;

    {   // stage 32 rows of X (coalesced float4)
        const float4* Xv = (const float4*)(X + row0 * K);
        float4* xtv = (float4*)(&xt[0][0]);
        const int n4 = 8 * K;  // 32*K/4
        for (int i = tid; i < n4; i += 256) xtv[i] = Xv[i];
    }
    __syncthreads();

    const int j2 = tid * 2;              // thread owns cols j2, j2+1
    float acc0[32], acc1[32];
    #pragma unroll
    for (int r = 0; r < 32; ++r) { acc0[r] = 0.f; acc1[r] = 0.f; }

    for (int k = 0; k < K; k += 4) {
        const float2 w0 = *(const float2*)&W[(k+0)*HH + j2];
        const float2 w1 = *(const float2*)&W[(k+1)*HH + j2];
        const float2 w2 = *(const float2*)&W[(k+2)*HH + j2];
        const float2 w3 = *(const float2*)&W[(k+3)*HH + j2];
        #pragma unroll
        for (int r = 0; r < 32; ++r) {
            const float4 xv = *(const float4*)&xt[r][k];   // LDS broadcast (free)
            acc0[r] += xv.x*w0.x + xv.y*w1.x + xv.z*w2.x + xv.w*w3.x;
            acc1[r] += xv.x*w0.y + xv.y*w1.y + xv.z*w2.y + xv.w*w3.y;
        }
    }
    const float2 bv = *(const float2*)&bias[j2];
    #pragma unroll
    for (int r = 0; r < 32; ++r) {
        float2 o; o.x = acc0[r] + bv.x; o.y = acc1[r] + bv.y;
        *(float2*)&OUT[(row0 + r) * HH + j2] = o;
    }
}

// ---------------- persistent recurrence: seq[c,t,:] : pre -> h, in-place ----------------
// 8 WGs per chain (batch), each owns a 64-col slice of Whh in VGPRs (wreg[64]/thread).
// Wave w == k-group w (k in [w*64,w*64+64)); lane l of wave w holds h[w*64+l] in hreg,
// broadcast via v_readlane. Cross-WG sync: monotonic per-chain atomic counter barrier
// (device scope) + double-buffered h broadcast buffer (a WG is at most 1 step ahead).
__global__ void __launch_bounds__(512)
rnn_recur(const float* __restrict__ Whh,
          float* seq, float* hTout,
          float* __restrict__ hbuf, unsigned int* __restrict__ cnt)
{
    __shared__ float lds_part[8][64];
    const int bid  = (int)blockIdx.x;
    const int c    = bid & 31;      // chain == batch; all 8 slices share bid%8 (XCD-local if round-robin)
    const int x    = bid >> 5;      // slice 0..7
    const int tid  = (int)threadIdx.x;
    const int lane = tid & 63;
    const int w    = tid >> 6;      // wave id == k-group
    const int J    = (x << 6) + lane;

    float wreg[64];                 // Whh[w*64+kk][J], pinned in VGPRs
    #pragma unroll
    for (int kk = 0; kk < 64; ++kk)
        wreg[kk] = Whh[((w << 6) + kk) * HH + J];

    float* hb = hbuf + c * (2 * HH);          // [2][512] per chain
    unsigned int* mycnt = cnt + (c << 6);     // 256B stride: no false sharing
    float* rowbase = seq + (long)c * TT * HH;

    float hreg = 0.f;                         // h[t-1][w*64+lane]; t=0 -> zeros
    float pre_cur = rowbase[J];               // pre[c,0,J] (uniform across waves)

    for (int t = 0; t < TT; ++t) {
        // MAC: partial[J] += sum_kk h[w*64+kk] * Whh[w*64+kk][J]  (pure VALU)
        float a0 = 0.f, a1 = 0.f, a2 = 0.f, a3 = 0.f;
        #pragma unroll
        for (int q = 0; q < 16; ++q) {
            a0 = fmaf(__uint_as_float(__builtin_amdgcn_readlane(__float_as_uint(hreg), 4*q+0)), wreg[4*q+0], a0);
            a1 = fmaf(__uint_as_float(__builtin_amdgcn_readlane(__float_as_uint(hreg), 4*q+1)), wreg[4*q+1], a1);
            a2 = fmaf(__uint_as_float(__builtin_amdgcn_readlane(__float_as_uint(hreg), 4*q+2)), wreg[4*q+2], a2);
            a3 = fmaf(__uint_as_float(__builtin_amdgcn_readlane(__float_as_uint(hreg), 4*q+3)), wreg[4*q+3], a3);
        }
        lds_part[w][lane] = (a0 + a1) + (a2 + a3);
        __syncthreads();

        if (tid < 64) {   // reduce 8 k-partials, activate, publish
            float s = pre_cur;
            #pragma unroll
            for (int q = 0; q < 8; ++q) s += lds_part[q][lane];
            const float hv = tanhf(s);
            rowbase[(long)t * HH + J] = hv;        // h out (overwrites consumed pre)
            hb[((t & 1) << 9) + J]    = hv;        // broadcast slot, parity t&1
            if (t == TT - 1) hTout[(c << 9) + J] = hv;
            __threadfence();                       // release our stores device-wide
        }
        // prefetch next pre (latency hides under the barrier spin)
        float pre_nxt = 0.f;
        if (t + 1 < TT) pre_nxt = rowbase[(long)(t + 1) * HH + J];
        __syncthreads();                           // all stores+fences done before arrive

        if (t + 1 < TT) {
            if (tid == 0) {
                __hip_atomic_fetch_add(mycnt, 1u, __ATOMIC_RELEASE, __HIP_MEMORY_SCOPE_AGENT);
                const unsigned int target = (unsigned)(t + 1) * 8u;
                while (__hip_atomic_load(mycnt, __ATOMIC_ACQUIRE, __HIP_MEMORY_SCOPE_AGENT) < target)
                    __builtin_amdgcn_s_sleep(1);
            }
            __syncthreads();
            __threadfence();                       // acquire: make hb reads fresh
            hreg = hb[((t & 1) << 9) + (w << 6) + lane];   // full h[t], my k-slot
        }
        pre_cur = pre_nxt;
    }
}

extern "C" void kernel_launch(void* const* d_in, const int* in_sizes, int n_in,
                              void* d_out, int out_size, void* d_ws, size_t ws_size,
                              hipStream_t stream) {
    const float* x    = (const float*)d_in[0];
    const float* Wih0 = (const float*)d_in[1];
    const float* Whh0 = (const float*)d_in[2];
    const float* b0   = (const float*)d_in[3];
    const float* Wih1 = (const float*)d_in[4];
    const float* Whh1 = (const float*)d_in[5];
    const float* b1   = (const float*)d_in[6];

    float* out = (float*)d_out;                       // [B,T,H] main + [2,B,H] tail
    float* hT  = out + (size_t)BB * TT * HH;

    // ws layout: [0,16K) barrier counters (2 layers x 32 chains x 256B), [16K, 16K+128K) hbuf
    unsigned int* cnt0 = (unsigned int*)d_ws;
    unsigned int* cnt1 = cnt0 + 32 * 64;
    float* hbuf = (float*)((char*)d_ws + 16384);

    hipMemsetAsync(d_ws, 0, 16384, stream);           // counters must start at 0 each call

    // 1) pre0 = x @ W_ih0 + b0   -> d_out main region (scratch)
    ih_gemm<256><<<dim3((BB * TT) / 32), dim3(256), 0, stream>>>(x, Wih0, b0, out);
    // 2) layer-0 recurrence, in-place pre0 -> h0; hT[0] tail
    rnn_recur<<<dim3(256), dim3(512), 0, stream>>>(Whh0, out, hT, hbuf, cnt0);
    // 3) pre1 = h0 @ W_ih1 + b1, in-place
    ih_gemm<512><<<dim3((BB * TT) / 32), dim3(256), 0, stream>>>(out, Wih1, b1, out);
    // 4) layer-1 recurrence, in-place pre1 -> h1 (final out); hT[1] tail
    rnn_recur<<<dim3(256), dim3(512), 0, stream>>>(Whh1, out, hT + BB * HH, hbuf, cnt1);
}

// Round 2
// 5932.084 us; speedup vs baseline: 26.1017x; 26.1017x over previous
//
#include <hip/hip_runtime.h>
#include <math.h>

#define TT 2048
#define BB 32
#define HH 512

// ---------------- input-projection GEMM: OUT[r,:] = X[r,:]@W + bias ----------------
// 32 rows per WG staged in LDS; safe for in-place X==OUT (each WG reads only its own
// rows, fully staged before any write).
template<int K>
__global__ void __launch_bounds__(256)
ih_gemm(const float* X, const float* __restrict__ W,
        const float* __restrict__ bias, float* OUT)
{
    __shared__ float xt[32][K];
    const int wg  = (int)blockIdx.x;
    const int tid = (int)threadIdx.x;
    const long row0 = (long)wg * 32;

    {   // stage 32 rows of X (coalesced float4)
        const float4* Xv = (const float4*)(X + row0 * K);
        float4* xtv = (float4*)(&xt[0][0]);
        const int n4 = 8 * K;  // 32*K/4
        for (int i = tid; i < n4; i += 256) xtv[i] = Xv[i];
    }
    __syncthreads();

    const int j2 = tid * 2;              // thread owns cols j2, j2+1
    float acc0[32], acc1[32];
    #pragma unroll
    for (int r = 0; r < 32; ++r) { acc0[r] = 0.f; acc1[r] = 0.f; }

    for (int k = 0; k < K; k += 4) {
        const float2 w0 = *(const float2*)&W[(k+0)*HH + j2];
        const float2 w1 = *(const float2*)&W[(k+1)*HH + j2];
        const float2 w2 = *(const float2*)&W[(k+2)*HH + j2];
        const float2 w3 = *(const float2*)&W[(k+3)*HH + j2];
        #pragma unroll
        for (int r = 0; r < 32; ++r) {
            const float4 xv = *(const float4*)&xt[r][k];   // LDS broadcast (free)
            acc0[r] += xv.x*w0.x + xv.y*w1.x + xv.z*w2.x + xv.w*w3.x;
            acc1[r] += xv.x*w0.y + xv.y*w1.y + xv.z*w2.y + xv.w*w3.y;
        }
    }
    const float2 bv = *(const float2*)&bias[j2];
    #pragma unroll
    for (int r = 0; r < 32; ++r) {
        float2 o; o.x = acc0[r] + bv.x; o.y = acc1[r] + bv.y;
        *(float2*)&OUT[(row0 + r) * HH + j2] = o;
    }
}

// ---------------- persistent recurrence: seq[c,t,:] : pre -> h, in-place ----------------
// 8 WGs per chain (batch). Each WG owns a 64-col slice of Whh in VGPRs (wreg[64]/thread,
// __launch_bounds__(512,2) so the allocator is allowed 256 VGPRs and does NOT spill).
// Wave w == k-group w; lane l of wave w holds h[w*64+l] in hreg, broadcast via readlane.
//
// Cross-WG exchange per step: each h element is published as ONE 8-byte relaxed
// agent-scope atomic {tag:32 | f32 value:32}, double-buffered by t&1. Consumers poll
// their own element until tag == tagbase+t. 8B single-copy atomicity replaces all
// release/acquire machinery: NO fences, NO acquire loads, NO separate flags -> no
// L2 writeback/invalidate storms (the round-1 killer).
//
// Safety of the 2-slot buffer (tag-chain): WG x writes slot s=t&1 at iter t only after
// all its waves observed tags >= t from ALL 8 WGs; a WG publishes tag t only after all
// ITS waves consumed h[t-1] (reads register-resident before sync1). Hence no producer
// can overwrite a slot some reader still needs, and no poll can be "lapped" to a
// wrong-match tag. Cross-replay staleness is killed by memset(hb2)=0 each call
// (tags wanted are always >= 1) + disjoint tag ranges per layer.
__global__ void __launch_bounds__(512, 2)
rnn_recur(const float* __restrict__ Whh,
          float* __restrict__ seq, float* __restrict__ hTout,
          unsigned long long* __restrict__ hb2, unsigned int tagbase)
{
    __shared__ float lds_part[8][64];
    const int bid  = (int)blockIdx.x;
    const int c    = bid & 31;      // chain == batch; 8 slices of chain c share bid%8
    const int x    = bid >> 5;      // slice 0..7
    const int tid  = (int)threadIdx.x;
    const int lane = tid & 63;
    const int w    = tid >> 6;      // wave id == k-group
    const int J    = (x << 6) + lane;

    float wreg[64];                 // Whh[w*64+kk][J], pinned in VGPRs
    #pragma unroll
    for (int kk = 0; kk < 64; ++kk)
        wreg[kk] = Whh[((w << 6) + kk) * HH + J];

    unsigned long long* hbc = hb2 + c * (2 * HH);   // [2][512] packed {tag|val}
    float* rowbase = seq + (long)c * TT * HH;

    float hreg = 0.f;                               // h[t-1][w*64+lane]; t=0 -> zeros
    float pre_cur = 0.f;
    if (tid < 64) pre_cur = rowbase[J];             // pre[c,0,J] (wave 0 only uses it)

    for (int t = 0; t < TT; ++t) {
        if (t > 0) {
            // wait for my element of h[t-1] (slice w, produced by WG w of this chain)
            const unsigned int want = tagbase + (unsigned)t;
            unsigned long long* myslot = hbc + (((t - 1) & 1) << 9) + (w << 6) + lane;
            unsigned long long pk = __hip_atomic_load(myslot, __ATOMIC_RELAXED, __HIP_MEMORY_SCOPE_AGENT);
            while ((unsigned)(pk >> 32) != want)
                pk = __hip_atomic_load(myslot, __ATOMIC_RELAXED, __HIP_MEMORY_SCOPE_AGENT);
            hreg = __uint_as_float((unsigned)(pk & 0xffffffffu));
        }

        // MAC: partial[J] += sum_kk h[w*64+kk] * Whh[w*64+kk][J]  (pure VALU)
        float a0 = 0.f, a1 = 0.f, a2 = 0.f, a3 = 0.f;
        #pragma unroll
        for (int q = 0; q < 16; ++q) {
            a0 = fmaf(__uint_as_float(__builtin_amdgcn_readlane(__float_as_uint(hreg), 4*q+0)), wreg[4*q+0], a0);
            a1 = fmaf(__uint_as_float(__builtin_amdgcn_readlane(__float_as_uint(hreg), 4*q+1)), wreg[4*q+1], a1);
            a2 = fmaf(__uint_as_float(__builtin_amdgcn_readlane(__float_as_uint(hreg), 4*q+2)), wreg[4*q+2], a2);
            a3 = fmaf(__uint_as_float(__builtin_amdgcn_readlane(__float_as_uint(hreg), 4*q+3)), wreg[4*q+3], a3);
        }
        lds_part[w][lane] = (a0 + a1) + (a2 + a3);
        __syncthreads();

        float s = 0.f;
        if (tid < 64) {   // reduce 8 k-partials (LDS reads must finish before sync2)
            s = pre_cur;
            #pragma unroll
            for (int q = 0; q < 8; ++q) s += lds_part[q][lane];
        }
        __syncthreads();  // frees lds_part for next iter's MAC by waves 1..7

        if (tid < 64) {
            const float hv = tanhf(s);
            rowbase[(long)t * HH + J] = hv;                // h out (overwrites consumed pre)
            if (t + 1 < TT) {
                const unsigned long long pk =
                    ((unsigned long long)(tagbase + (unsigned)(t + 1)) << 32)
                    | (unsigned long long)__float_as_uint(hv);
                __hip_atomic_store(hbc + (((t & 1) << 9) + J), pk,
                                   __ATOMIC_RELAXED, __HIP_MEMORY_SCOPE_AGENT);
                pre_cur = rowbase[(long)(t + 1) * HH + J]; // prefetch hides under next poll
            } else {
                hTout[(c << 9) + J] = hv;                  // final hidden state
            }
        }
    }
}

extern "C" void kernel_launch(void* const* d_in, const int* in_sizes, int n_in,
                              void* d_out, int out_size, void* d_ws, size_t ws_size,
                              hipStream_t stream) {
    const float* x    = (const float*)d_in[0];
    const float* Wih0 = (const float*)d_in[1];
    const float* Whh0 = (const float*)d_in[2];
    const float* b0   = (const float*)d_in[3];
    const float* Wih1 = (const float*)d_in[4];
    const float* Whh1 = (const float*)d_in[5];
    const float* b1   = (const float*)d_in[6];

    float* out = (float*)d_out;                       // [B,T,H] main + [2,B,H] tail
    float* hT  = out + (size_t)BB * TT * HH;

    // ws: [0, 256K) = hb2 packed {tag|value} broadcast buffer, 32 chains x 2 x 512 x 8B
    unsigned long long* hb2 = (unsigned long long*)d_ws;
    // Clear tags every call: replays reuse ws without re-poisoning, and a stale tag
    // from the previous replay would exactly match this replay's wanted tag.
    hipMemsetAsync(d_ws, 0, BB * 2 * HH * sizeof(unsigned long long), stream);

    // 1) pre0 = x @ W_ih0 + b0   -> d_out main region (scratch)
    ih_gemm<256><<<dim3((BB * TT) / 32), dim3(256), 0, stream>>>(x, Wih0, b0, out);
    // 2) layer-0 recurrence, in-place pre0 -> h0; hT[0] tail  (tags 1..2047)
    rnn_recur<<<dim3(256), dim3(512), 0, stream>>>(Whh0, out, hT, hb2, 0u);
    // 3) pre1 = h0 @ W_ih1 + b1, in-place
    ih_gemm<512><<<dim3((BB * TT) / 32), dim3(256), 0, stream>>>(out, Wih1, b1, out);
    // 4) layer-1 recurrence, in-place pre1 -> h1 (final out); hT[1] tail (tags 4097..)
    rnn_recur<<<dim3(256), dim3(512), 0, stream>>>(Whh1, out, hT + BB * HH, hb2, 4096u);
}

// Round 4
// 5666.357 us; speedup vs baseline: 27.3258x; 1.0469x over previous
//
#include <hip/hip_runtime.h>
#include <math.h>

#define TT 2048
#define BB 32
#define HH 512

// ---------------- input-projection GEMM: OUT[r,:] = X[r,:]@W + bias ----------------
// 32 rows per WG staged in LDS; safe for in-place X==OUT (each WG reads only its own
// rows, fully staged before any write).
template<int K>
__global__ void __launch_bounds__(256)
ih_gemm(const float* X, const float* __restrict__ W,
        const float* __restrict__ bias, float* OUT)
{
    __shared__ float xt[32][K];
    const int wg  = (int)blockIdx.x;
    const int tid = (int)threadIdx.x;
    const long row0 = (long)wg * 32;

    {   // stage 32 rows of X (coalesced float4)
        const float4* Xv = (const float4*)(X + row0 * K);
        float4* xtv = (float4*)(&xt[0][0]);
        const int n4 = 8 * K;  // 32*K/4
        for (int i = tid; i < n4; i += 256) xtv[i] = Xv[i];
    }
    __syncthreads();

    const int j2 = tid * 2;              // thread owns cols j2, j2+1
    float acc0[32], acc1[32];
    #pragma unroll
    for (int r = 0; r < 32; ++r) { acc0[r] = 0.f; acc1[r] = 0.f; }

    for (int k = 0; k < K; k += 4) {
        const float2 w0 = *(const float2*)&W[(k+0)*HH + j2];
        const float2 w1 = *(const float2*)&W[(k+1)*HH + j2];
        const float2 w2 = *(const float2*)&W[(k+2)*HH + j2];
        const float2 w3 = *(const float2*)&W[(k+3)*HH + j2];
        #pragma unroll
        for (int r = 0; r < 32; ++r) {
            const float4 xv = *(const float4*)&xt[r][k];   // LDS broadcast (free)
            acc0[r] += xv.x*w0.x + xv.y*w1.x + xv.z*w2.x + xv.w*w3.x;
            acc1[r] += xv.x*w0.y + xv.y*w1.y + xv.z*w2.y + xv.w*w3.y;
        }
    }
    const float2 bv = *(const float2*)&bias[j2];
    #pragma unroll
    for (int r = 0; r < 32; ++r) {
        float2 o; o.x = acc0[r] + bv.x; o.y = acc1[r] + bv.y;
        *(float2*)&OUT[(row0 + r) * HH + j2] = o;
    }
}

// ---------------- persistent recurrence: seq[c,t,:] : pre -> h, in-place ----------------
// 8 WGs per chain (batch). Each WG owns a 64-col slice of Whh, pinned in VGPRs via an
// empty asm "+v" per element (compiler cannot sink/remat the loads into the t-loop);
// __launch_bounds__(512,2) grants a 256-VGPR budget so ~110 live regs fit without spill.
//
// Wave w == k-group w; lane l of wave w holds h[w*64+l] in hreg, broadcast via readlane.
// Cross-WG exchange per step: 8-byte relaxed agent-scope atomic {tag:32 | f32:32},
// double-buffered by t&1; consumers poll their own element until the tag matches. 8B
// single-copy atomicity replaces all fences (round-1 killer: agent fences = L2 flushes).
//
// ONE __syncthreads per step + LDS partials double-buffered by parity. Round-3 bug:
// with a single shared lds_part, wave w of WG x at iter t+1 is gated only by WG w's
// publish (not by WG x's wave-0 reduce) -> distance-1 WAR overwrite of lds_part before
// wave 0 read it. Parity fixes distance-1 (different buffer); the barrier at t+1 fixes
// distance-2 (wave 0 arrives there only after its iter-t reads).
//
// hb2 slot-overwrite safety (tag-chain, unchanged): WG x overwrites a slot (tag t-1 ->
// t+1) only after its poll observed tag t from ALL WGs; WG y publishes tag t only after
// barrier(t-1), i.e. after ALL its waves consumed tag t-1. So no live value is ever
// overwritten, and disjoint per-layer tag ranges + memset-per-call kill replay staleness.
__global__ void __launch_bounds__(512, 2)
rnn_recur(const float* __restrict__ Whh,
          float* __restrict__ seq, float* __restrict__ hTout,
          unsigned long long* __restrict__ hb2, unsigned int tagbase)
{
    __shared__ float lds_part[2][8][64];   // [parity][wave][lane]
    const int bid  = (int)blockIdx.x;
    const int c    = bid & 31;      // chain == batch; 8 slices of chain c share bid%8
    const int x    = bid >> 5;      // slice 0..7
    const int tid  = (int)threadIdx.x;
    const int lane = tid & 63;
    const int w    = tid >> 6;      // wave id == k-group
    const int J    = (x << 6) + lane;

    float wreg[64];                 // Whh[w*64+kk][J]
    #pragma unroll
    for (int kk = 0; kk < 64; ++kk)
        wreg[kk] = Whh[((w << 6) + kk) * HH + J];
    #pragma unroll
    for (int kk = 0; kk < 64; ++kk)
        asm volatile("" : "+v"(wreg[kk]));   // pin: opaque defs, must stay in VGPRs

    unsigned long long* hbc = hb2 + c * (2 * HH);   // [2][512] packed {tag|val}
    float* rowbase = seq + (long)c * TT * HH;

    float hreg = 0.f;                               // h[t-1][w*64+lane]; t=0 -> zeros
    float pre_cur = 0.f;
    if (tid < 64) pre_cur = rowbase[J];             // pre[c,0,J] (only wave 0 uses it)

    for (int t = 0; t < TT; ++t) {
        const int p = t & 1;
        if (t > 0) {
            // wait for my element of h[t-1] (produced by WG w of this chain)
            const unsigned int want = tagbase + (unsigned)t;
            unsigned long long* myslot = hbc + (((t - 1) & 1) << 9) + (w << 6) + lane;
            unsigned long long pk = __hip_atomic_load(myslot, __ATOMIC_RELAXED, __HIP_MEMORY_SCOPE_AGENT);
            while ((unsigned)(pk >> 32) != want)
                pk = __hip_atomic_load(myslot, __ATOMIC_RELAXED, __HIP_MEMORY_SCOPE_AGENT);
            hreg = __uint_as_float((unsigned)(pk & 0xffffffffu));
        }

        // MAC: partial[J] += sum_kk h[w*64+kk] * Whh[w*64+kk][J]  (pure VALU, W resident)
        float a0 = 0.f, a1 = 0.f, a2 = 0.f, a3 = 0.f;
        #pragma unroll
        for (int q = 0; q < 16; ++q) {
            a0 = fmaf(__uint_as_float(__builtin_amdgcn_readlane(__float_as_uint(hreg), 4*q+0)), wreg[4*q+0], a0);
            a1 = fmaf(__uint_as_float(__builtin_amdgcn_readlane(__float_as_uint(hreg), 4*q+1)), wreg[4*q+1], a1);
            a2 = fmaf(__uint_as_float(__builtin_amdgcn_readlane(__float_as_uint(hreg), 4*q+2)), wreg[4*q+2], a2);
            a3 = fmaf(__uint_as_float(__builtin_amdgcn_readlane(__float_as_uint(hreg), 4*q+3)), wreg[4*q+3], a3);
        }
        lds_part[p][w][lane] = (a0 + a1) + (a2 + a3);
        __syncthreads();   // the ONLY barrier per step

        if (tid < 64) {
            float s = pre_cur;
            #pragma unroll
            for (int q = 0; q < 8; ++q) s += lds_part[p][q][lane];
            // tanh(s) = 1 - 2/(e^{2s}+1); exp-based, ~2e-7 abs err, inf-safe both tails
            const float e  = __expf(2.0f * s);
            const float hv = 1.0f - 2.0f / (e + 1.0f);
            if (t + 1 < TT) {
                // publish FIRST: it's the cross-WG critical path
                const unsigned long long pk =
                    ((unsigned long long)(tagbase + (unsigned)(t + 1)) << 32)
                    | (unsigned long long)__float_as_uint(hv);
                __hip_atomic_store(hbc + ((p << 9) + J), pk,
                                   __ATOMIC_RELAXED, __HIP_MEMORY_SCOPE_AGENT);
                rowbase[(long)t * HH + J] = hv;            // h out (overwrites consumed pre)
                pre_cur = rowbase[(long)(t + 1) * HH + J]; // prefetch hides under next poll
            } else {
                rowbase[(long)t * HH + J] = hv;
                hTout[(c << 9) + J] = hv;                  // final hidden state
            }
        }
    }
}

extern "C" void kernel_launch(void* const* d_in, const int* in_sizes, int n_in,
                              void* d_out, int out_size, void* d_ws, size_t ws_size,
                              hipStream_t stream) {
    const float* x    = (const float*)d_in[0];
    const float* Wih0 = (const float*)d_in[1];
    const float* Whh0 = (const float*)d_in[2];
    const float* b0   = (const float*)d_in[3];
    const float* Wih1 = (const float*)d_in[4];
    const float* Whh1 = (const float*)d_in[5];
    const float* b1   = (const float*)d_in[6];

    float* out = (float*)d_out;                       // [B,T,H] main + [2,B,H] tail
    float* hT  = out + (size_t)BB * TT * HH;

    // ws: [0, 256K) = hb2 packed {tag|value} broadcast buffer, 32 chains x 2 x 512 x 8B
    unsigned long long* hb2 = (unsigned long long*)d_ws;
    // Clear tags every call: graph replays reuse ws un-poisoned, and a stale tag from
    // the previous replay would exactly match this replay's wanted tag.
    hipMemsetAsync(d_ws, 0, BB * 2 * HH * sizeof(unsigned long long), stream);

    // 1) pre0 = x @ W_ih0 + b0   -> d_out main region (scratch)
    ih_gemm<256><<<dim3((BB * TT) / 32), dim3(256), 0, stream>>>(x, Wih0, b0, out);
    // 2) layer-0 recurrence, in-place pre0 -> h0; hT[0] tail  (tags 1..2047)
    rnn_recur<<<dim3(256), dim3(512), 0, stream>>>(Whh0, out, hT, hb2, 0u);
    // 3) pre1 = h0 @ W_ih1 + b1, in-place
    ih_gemm<512><<<dim3((BB * TT) / 32), dim3(256), 0, stream>>>(out, Wih1, b1, out);
    // 4) layer-1 recurrence, in-place pre1 -> h1 (final out); hT[1] tail (tags 4097..6143)
    rnn_recur<<<dim3(256), dim3(512), 0, stream>>>(Whh1, out, hT + BB * HH, hb2, 4096u);
}

// Round 5
// 5624.252 us; speedup vs baseline: 27.5304x; 1.0075x over previous
//
#include <hip/hip_runtime.h>
#include <math.h>

#define TT 2048
#define BB 32
#define HH 512

// ---------------- input-projection GEMM: OUT[r,:] = X[r,:]@W + bias ----------------
// 32 rows per WG staged in LDS; safe for in-place X==OUT (each WG reads only its own
// rows, fully staged before any write).
template<int K>
__global__ void __launch_bounds__(256)
ih_gemm(const float* X, const float* __restrict__ W,
        const float* __restrict__ bias, float* OUT)
{
    __shared__ float xt[32][K];
    const int wg  = (int)blockIdx.x;
    const int tid = (int)threadIdx.x;
    const long row0 = (long)wg * 32;

    {   // stage 32 rows of X (coalesced float4)
        const float4* Xv = (const float4*)(X + row0 * K);
        float4* xtv = (float4*)(&xt[0][0]);
        const int n4 = 8 * K;  // 32*K/4
        for (int i = tid; i < n4; i += 256) xtv[i] = Xv[i];
    }
    __syncthreads();

    const int j2 = tid * 2;              // thread owns cols j2, j2+1
    float acc0[32], acc1[32];
    #pragma unroll
    for (int r = 0; r < 32; ++r) { acc0[r] = 0.f; acc1[r] = 0.f; }

    for (int k = 0; k < K; k += 4) {
        const float2 w0 = *(const float2*)&W[(k+0)*HH + j2];
        const float2 w1 = *(const float2*)&W[(k+1)*HH + j2];
        const float2 w2 = *(const float2*)&W[(k+2)*HH + j2];
        const float2 w3 = *(const float2*)&W[(k+3)*HH + j2];
        #pragma unroll
        for (int r = 0; r < 32; ++r) {
            const float4 xv = *(const float4*)&xt[r][k];   // LDS broadcast (free)
            acc0[r] += xv.x*w0.x + xv.y*w1.x + xv.z*w2.x + xv.w*w3.x;
            acc1[r] += xv.x*w0.y + xv.y*w1.y + xv.z*w2.y + xv.w*w3.y;
        }
    }
    const float2 bv = *(const float2*)&bias[j2];
    #pragma unroll
    for (int r = 0; r < 32; ++r) {
        float2 o; o.x = acc0[r] + bv.x; o.y = acc1[r] + bv.y;
        *(float2*)&OUT[(row0 + r) * HH + j2] = o;
    }
}

// ---------------- persistent recurrence: seq[c,t,:] : pre -> h, in-place ----------------
// 8 WGs per chain (batch). Each WG owns a 64-col slice of Whh held in 16 NAMED float4
// SSA values (wv0..wv15) — no local array, nothing for SROA to leave in scratch.
// Rounds 1-4 failure: `float wreg[64]` was never promoted (dynamic index before unroll
// -> alloca -> scratch; VGPR_Count stuck at 44, W re-read from L2/HBM every step).
// A 4-operand asm pin per float4 keeps the loads hoisted (cannot re-sink into t-loop).
//
// Wave w == k-group w; lane l of wave w holds h[w*64+l] in hreg, broadcast via readlane.
// Cross-WG exchange per step: 8-byte relaxed agent-scope atomic {tag:32 | f32:32},
// double-buffered by t&1; consumers poll their own element until the tag matches. 8B
// single-copy atomicity replaces all fences (round-1 killer: agent fences = L2 flushes).
//
// ONE __syncthreads per step + LDS partials double-buffered by parity (round-3 race
// fix): distance-1 WAR goes to the other parity buffer; distance-2 is ordered by the
// barrier (wave 0 reaches barrier(t+1) only after its iter-t reduce reads).
//
// hb2 slot-overwrite safety (tag-chain): a WG overwrites a slot (tag t -> t+2) only
// after observing tag t+1 from ALL WGs, which requires every WG's waves to have
// consumed tag t. Disjoint per-layer tag ranges + memset-per-call kill replay staleness.
__global__ void __launch_bounds__(512, 2)
rnn_recur(const float* __restrict__ Whh,
          float* __restrict__ seq, float* __restrict__ hTout,
          unsigned long long* __restrict__ hb2, unsigned int tagbase)
{
    __shared__ float lds_part[2][8][64];   // [parity][wave][lane]
    const int bid  = (int)blockIdx.x;
    const int c    = bid & 31;      // chain == batch; all 8 slices of chain c share bid%8
    const int x    = bid >> 5;      // slice 0..7
    const int tid  = (int)threadIdx.x;
    const int lane = tid & 63;
    const int w    = tid >> 6;      // wave id == k-group
    const int J    = (x << 6) + lane;

    // ---- W slice as 16 named float4 SSA values (64 VGPRs, guaranteed promotable) ----
    const long wb = (long)(w << 6) * HH + J;   // &Whh[(w*64 + kk)*HH + J], kk stride HH
    float4 wv0, wv1, wv2, wv3, wv4, wv5, wv6, wv7,
           wv8, wv9, wv10, wv11, wv12, wv13, wv14, wv15;
#define LOADW(q) do { \
        wv##q.x = Whh[wb + (4*q+0)*HH]; wv##q.y = Whh[wb + (4*q+1)*HH]; \
        wv##q.z = Whh[wb + (4*q+2)*HH]; wv##q.w = Whh[wb + (4*q+3)*HH]; } while (0)
    LOADW(0);  LOADW(1);  LOADW(2);  LOADW(3);
    LOADW(4);  LOADW(5);  LOADW(6);  LOADW(7);
    LOADW(8);  LOADW(9);  LOADW(10); LOADW(11);
    LOADW(12); LOADW(13); LOADW(14); LOADW(15);
#undef LOADW
#define PINW(q) asm volatile("" : "+v"(wv##q.x), "+v"(wv##q.y), "+v"(wv##q.z), "+v"(wv##q.w))
    PINW(0);  PINW(1);  PINW(2);  PINW(3);
    PINW(4);  PINW(5);  PINW(6);  PINW(7);
    PINW(8);  PINW(9);  PINW(10); PINW(11);
    PINW(12); PINW(13); PINW(14); PINW(15);
#undef PINW

    unsigned long long* hbc = hb2 + c * (2 * HH);   // [2][512] packed {tag|val}
    float* rowbase = seq + (long)c * TT * HH;

    float hreg = 0.f;                               // h[t-1][w*64+lane]; t=0 -> zeros
    float pre_cur = 0.f;
    if (tid < 64) pre_cur = rowbase[J];             // pre[c,0,J] (only wave 0 uses it)

    for (int t = 0; t < TT; ++t) {
        const int p = t & 1;
        if (t > 0) {
            // wait for my element of h[t-1] (produced by WG w of this chain)
            const unsigned int want = tagbase + (unsigned)t;
            unsigned long long* myslot = hbc + (((t - 1) & 1) << 9) + (w << 6) + lane;
            unsigned long long pk = __hip_atomic_load(myslot, __ATOMIC_RELAXED, __HIP_MEMORY_SCOPE_AGENT);
            while ((unsigned)(pk >> 32) != want)
                pk = __hip_atomic_load(myslot, __ATOMIC_RELAXED, __HIP_MEMORY_SCOPE_AGENT);
            hreg = __uint_as_float((unsigned)(pk & 0xffffffffu));
        }

        // MAC: partial[J] += sum_kk h[w*64+kk] * W[kk] — register-resident W, readlane h
        const unsigned hbits = __float_as_uint(hreg);
        float a0 = 0.f, a1 = 0.f, a2 = 0.f, a3 = 0.f;
#define BCAST(i) __uint_as_float(__builtin_amdgcn_readlane(hbits, (i)))
#define MACQ(q) do { \
        a0 = fmaf(BCAST(4*q+0), wv##q.x, a0); \
        a1 = fmaf(BCAST(4*q+1), wv##q.y, a1); \
        a2 = fmaf(BCAST(4*q+2), wv##q.z, a2); \
        a3 = fmaf(BCAST(4*q+3), wv##q.w, a3); } while (0)
        MACQ(0);  MACQ(1);  MACQ(2);  MACQ(3);
        MACQ(4);  MACQ(5);  MACQ(6);  MACQ(7);
        MACQ(8);  MACQ(9);  MACQ(10); MACQ(11);
        MACQ(12); MACQ(13); MACQ(14); MACQ(15);
#undef MACQ
#undef BCAST
        lds_part[p][w][lane] = (a0 + a1) + (a2 + a3);
        __syncthreads();   // the ONLY barrier per step

        if (tid < 64) {
            float s = pre_cur;
            #pragma unroll
            for (int q = 0; q < 8; ++q) s += lds_part[p][q][lane];
            // tanh(s) = 1 - 2/(e^{2s}+1); exp-based, ~2e-7 abs err, inf-safe both tails
            const float e  = __expf(2.0f * s);
            const float hv = 1.0f - 2.0f / (e + 1.0f);
            if (t + 1 < TT) {
                // publish FIRST: it's the cross-WG critical path
                const unsigned long long pk =
                    ((unsigned long long)(tagbase + (unsigned)(t + 1)) << 32)
                    | (unsigned long long)__float_as_uint(hv);
                __hip_atomic_store(hbc + ((p << 9) + J), pk,
                                   __ATOMIC_RELAXED, __HIP_MEMORY_SCOPE_AGENT);
                rowbase[(long)t * HH + J] = hv;            // h out (overwrites consumed pre)
                pre_cur = rowbase[(long)(t + 1) * HH + J]; // prefetch hides under next poll
            } else {
                rowbase[(long)t * HH + J] = hv;
                hTout[(c << 9) + J] = hv;                  // final hidden state
            }
        }
    }
}

extern "C" void kernel_launch(void* const* d_in, const int* in_sizes, int n_in,
                              void* d_out, int out_size, void* d_ws, size_t ws_size,
                              hipStream_t stream) {
    const float* x    = (const float*)d_in[0];
    const float* Wih0 = (const float*)d_in[1];
    const float* Whh0 = (const float*)d_in[2];
    const float* b0   = (const float*)d_in[3];
    const float* Wih1 = (const float*)d_in[4];
    const float* Whh1 = (const float*)d_in[5];
    const float* b1   = (const float*)d_in[6];

    float* out = (float*)d_out;                       // [B,T,H] main + [2,B,H] tail
    float* hT  = out + (size_t)BB * TT * HH;

    // ws: [0, 256K) = hb2 packed {tag|value} broadcast buffer, 32 chains x 2 x 512 x 8B
    unsigned long long* hb2 = (unsigned long long*)d_ws;
    // Clear tags every call: graph replays reuse ws un-poisoned, and a stale tag from
    // the previous replay would exactly match this replay's wanted tag.
    hipMemsetAsync(d_ws, 0, BB * 2 * HH * sizeof(unsigned long long), stream);

    // 1) pre0 = x @ W_ih0 + b0   -> d_out main region (scratch)
    ih_gemm<256><<<dim3((BB * TT) / 32), dim3(256), 0, stream>>>(x, Wih0, b0, out);
    // 2) layer-0 recurrence, in-place pre0 -> h0; hT[0] tail  (tags 1..2047)
    rnn_recur<<<dim3(256), dim3(512), 0, stream>>>(Whh0, out, hT, hb2, 0u);
    // 3) pre1 = h0 @ W_ih1 + b1, in-place
    ih_gemm<512><<<dim3((BB * TT) / 32), dim3(256), 0, stream>>>(out, Wih1, b1, out);
    // 4) layer-1 recurrence, in-place pre1 -> h1 (final out); hT[1] tail (tags 4097..6143)
    rnn_recur<<<dim3(256), dim3(512), 0, stream>>>(Whh1, out, hT + BB * HH, hb2, 4096u);
}